// Round 7
// baseline (182.937 us; speedup 1.0000x reference)
//
#include <hip/hip_runtime.h>
#include <math.h>
#include <string.h>

#define CDIM 64
#define LDSW 72   // row stride in bf16 elems (144 B): b128 frag reads measured conflict-free
#define DEG  5    // Chebyshev tail on [1,7.5] ~5.6e-3; Paterson-Stockmeyer s=2 -> 3 matmuls

struct Coefs { float a[DEG + 1]; float cc; float inv_h; };

typedef __attribute__((ext_vector_type(8)))  short short8;    // 8 bf16 = 4 VGPRs (MFMA A/B frag)
typedef __attribute__((ext_vector_type(16))) float floatx16;  // MFMA C/D

// Row-major hi/lo store of one fp32 as two bf16 (truncation split).
// Per instruction: half-wave writes 32 consecutive u16 of row q, other half
// row q+4 -> in-dword lane merge: 0 conflicts (measured R2).
__device__ __forceinline__ void st_hilo(unsigned short* __restrict__ Dh,
                                        unsigned short* __restrict__ Dl,
                                        int idx, float x) {
  const unsigned u = __builtin_bit_cast(unsigned, x);
  const float h = __builtin_bit_cast(float, u & 0xFFFF0000u);
  const float l = x - h;                       // exact
  const unsigned ul = __builtin_bit_cast(unsigned, l);
  Dh[idx] = (unsigned short)(u >> 16);
  Dl[idx] = (unsigned short)(ul >> 16);
}

// hi-only store with round-to-nearest (2^-9 err vs 2^-8 truncation).
__device__ __forceinline__ void st_h_rn(unsigned short* __restrict__ Dh,
                                        int idx, float x) {
  const unsigned u = __builtin_bit_cast(unsigned, x);
  Dh[idx] = (unsigned short)((u + 0x7FFFu + ((u >> 16) & 1u)) >> 16);
}

// Scalar hi/lo read back to f32 (~2^-17 rel error vs stored value).
__device__ __forceinline__ float ld_hilo(const unsigned short* __restrict__ Ph,
                                         const unsigned short* __restrict__ Pl,
                                         int idx) {
  const float h = __builtin_bit_cast(float, ((unsigned)Ph[idx]) << 16);
  const float l = __builtin_bit_cast(float, ((unsigned)Pl[idx]) << 16);
  return h + l;
}

struct Frags  { short8 h[4]; short8 l[4]; };   // hi+lo fragments = 32 VGPRs
struct FragsH { short8 h[4]; };                // hi-only fragments = 16 VGPRs

__device__ __forceinline__ void load_frags(const unsigned short* __restrict__ Ph,
                                           const unsigned short* __restrict__ Pl,
                                           int row, int ko, Frags* f) {
#pragma unroll
  for (int kk = 0; kk < 4; ++kk) {
    f->h[kk] = *(const short8*)(Ph + row * LDSW + kk * 16 + ko);
    f->l[kk] = *(const short8*)(Pl + row * LDSW + kk * 16 + ko);
  }
}

__device__ __forceinline__ void load_frags_h(const unsigned short* __restrict__ Ph,
                                             int row, int ko, FragsH* f) {
#pragma unroll
  for (int kk = 0; kk < 4; ++kk)
    f->h[kk] = *(const short8*)(Ph + row * LDSW + kk * 16 + ko);
}

// Single-chain h*h 32x32 tile product (downstream matmuls: dropped l-terms
// are ~2^-9-relative, scaled by small coefficients -> ~1e-3 output error).
__device__ __forceinline__ floatx16 mm_h(const FragsH& a, const FragsH& b) {
  floatx16 c;
#pragma unroll
  for (int i = 0; i < 16; ++i) c[i] = 0.0f;
#pragma unroll
  for (int kk = 0; kk < 4; ++kk)
    c = __builtin_amdgcn_mfma_f32_32x32x16_bf16(a.h[kk], b.h[kk], c, 0, 0, 0);
  return c;
}

// launch_bounds(256,5): R6 measured occupancy ~40% (4 blocks/CU) at LDS 27.6KB
// which permits 5. True peak live set is ~80 regs (mm1: fa 32v + fb slabs 8v +
// c1,c2 32acc; post-mm1: accM2+accT 32acc + fah/fm2 32v), so the 5-wave budget
// (<=102 regs) fits without spill. WRITE_SIZE growth = spill signature = revert.
__global__ void __launch_bounds__(256, 5)
logm_kernel(const float* __restrict__ X, float* __restrict__ Y, Coefs cf) {
  // Buffers: A(hi+lo) = M1 (never overwritten), Ch = M2 then Q1 (hi-only, RN).
  // 3 x 9216 B = 27.6 KB -> 5 blocks/CU.
  __shared__ __align__(16) unsigned short Ah[CDIM * LDSW], Al[CDIM * LDSW];
  __shared__ __align__(16) unsigned short Ch[CDIM * LDSW];

  const int tid  = threadIdx.x;
  const int lane = tid & 63;
  const int w    = tid >> 6;
  const int m    = blockIdx.x;

  const float* __restrict__ Xm = X + (size_t)m * (CDIM * CDIM);
  float* __restrict__ Ym       = Y + (size_t)m * (CDIM * CDIM);

  const int R    = (w >> 1) * 32;
  const int Cc   = (w & 1) * 32;
  const int l31  = lane & 31;
  const int half = lane >> 5;
  const int arow = R + l31;
  const int brow = Cc + l31;
  const int ko   = half * 8;
  const int col  = Cc + l31;
  int rows[16];  // C/D layout: row = (r&3) + 8*(r>>2) + 4*half  [verified m74/m101]
#pragma unroll
  for (int r = 0; r < 16; ++r) rows[r] = R + (r & 3) + 8 * (r >> 2) + 4 * half;

  // ---- stage: load X once in C-layout (coalesced 2x128B per instr), M1 -> A hi/lo ----
#pragma unroll
  for (int r = 0; r < 16; ++r) {
    float x = Xm[rows[r] * CDIM + col];
    if (rows[r] == col) x -= cf.cc;
    st_hilo(Ah, Al, rows[r] * LDSW + col, x * cf.inv_h);
  }
  __syncthreads();

  // ---- mm1: M2 = M1*M1 (full 3-chain compensation; feeds 2 more multiplies).
  //      fa loaded whole (h half reused as mm2's A-operand); fb slab-wise to
  //      cap the register peak. Branch-free: diagonal waves just re-read fa's
  //      rows via brow (broadcast-friendly, M1 symmetric). ----
  Frags fa;
  load_frags(Ah, Al, arow, ko, &fa);
  floatx16 c1, c2;
#pragma unroll
  for (int i = 0; i < 16; ++i) { c1[i] = 0.0f; c2[i] = 0.0f; }
#pragma unroll
  for (int kk = 0; kk < 4; ++kk) {
    const short8 fbh = *(const short8*)(Ah + brow * LDSW + kk * 16 + ko);
    const short8 fbl = *(const short8*)(Al + brow * LDSW + kk * 16 + ko);
    c1 = __builtin_amdgcn_mfma_f32_32x32x16_bf16(fa.h[kk], fbh, c1, 0, 0, 0);
    c2 = __builtin_amdgcn_mfma_f32_32x32x16_bf16(fa.h[kk], fbl, c2, 0, 0, 0);
    c2 = __builtin_amdgcn_mfma_f32_32x32x16_bf16(fa.l[kk], fbh, c2, 0, 0, 0);
  }
  floatx16 accM2;
#pragma unroll
  for (int i = 0; i < 16; ++i) accM2[i] = c1[i] + c2[i];
#pragma unroll
  for (int r = 0; r < 16; ++r) st_h_rn(Ch, rows[r] * LDSW + col, accM2[r]);
  __syncthreads();   // M2 (hi, RN) published; all A reads for mm1 done

  // ---- mm2: T = M1*M2 (h-only; fa.h reused, fa.l dead);
  //      Q1 = a5*T + a4*accM2(f32 exact) + a3*M1(hi/lo) + a2*I ----
  FragsH fah, fm2;
#pragma unroll
  for (int kk = 0; kk < 4; ++kk) fah.h[kk] = fa.h[kk];
  load_frags_h(Ch, brow, ko, &fm2);      // M2 B-operand via symmetry; kept for mm3
  floatx16 accT = mm_h(fah, fm2);
  __syncthreads();                       // all Ch (M2) cross-tile reads complete
#pragma unroll
  for (int r = 0; r < 16; ++r) {
    const int idx = rows[r] * LDSW + col;
    float q = cf.a[5] * accT[r] + cf.a[4] * accM2[r] + cf.a[3] * ld_hilo(Ah, Al, idx);
    if (rows[r] == col) q += cf.a[2];
    st_h_rn(Ch, idx, q);                 // Q1 over M2 (hi-only, RN)
  }
  __syncthreads();

  // ---- mm3: out = Q1*M2 (h-only) + a1*M1(hi/lo) + a0*I -> global ----
  FragsH fq1;
  load_frags_h(Ch, arow, ko, &fq1);
  floatx16 accF = mm_h(fq1, fm2);
#pragma unroll
  for (int r = 0; r < 16; ++r) {
    float p = accF[r] + cf.a[1] * ld_hilo(Ah, Al, rows[r] * LDSW + col);
    if (rows[r] == col) p += cf.a[0];
    Ym[rows[r] * CDIM + col] = p;        // 2x128B coalesced per instr
  }
}

extern "C" void kernel_launch(void* const* d_in, const int* in_sizes, int n_in,
                              void* d_out, int out_size, void* d_ws, size_t ws_size,
                              hipStream_t stream) {
  const float* X = (const float*)d_in[0];
  float* Y = (float*)d_out;
  const int nmat = in_sizes[0] / (CDIM * CDIM);

  // Chebyshev coefficients of log on [lo,hi] -> monomial basis in t=(x-cc)/hh.
  // Analytic: log(cc+hh*t) = log(A) - 2*sum_k z^k/k T_k(t),  z=(-cc+sqrt(cc^2-hh^2))/hh
  Coefs cf;
  {
    const double lo = 1.0, hi = 7.5;
    const double cc = 0.5 * (lo + hi), hh = 0.5 * (hi - lo);
    const double s  = sqrt(cc * cc - hh * hh);
    const double z  = (-cc + s) / hh;
    const double A  = 0.5 * (cc + s);
    double cheb[DEG + 1];
    cheb[0] = log(A);
    double zp = 1.0;
    for (int k = 1; k <= DEG; ++k) { zp *= z; cheb[k] = -2.0 * zp / (double)k; }
    double mono[DEG + 1], Tprev[DEG + 1], Tcur[DEG + 1];
    memset(mono, 0, sizeof(mono));
    memset(Tprev, 0, sizeof(Tprev));
    memset(Tcur, 0, sizeof(Tcur));
    Tprev[0] = 1.0; mono[0] += cheb[0];
    Tcur[1]  = 1.0; mono[1] += cheb[1];
    for (int k = 2; k <= DEG; ++k) {
      double Tn[DEG + 1];
      memset(Tn, 0, sizeof(Tn));
      for (int j = 0; j <= k; ++j) {
        double v = -Tprev[j];
        if (j > 0) v += 2.0 * Tcur[j - 1];
        Tn[j] = v;
      }
      for (int j = 0; j <= k; ++j) mono[j] += cheb[k] * Tn[j];
      for (int j = 0; j <= DEG; ++j) { Tprev[j] = Tcur[j]; Tcur[j] = Tn[j]; }
    }
    for (int i = 0; i <= DEG; ++i) cf.a[i] = (float)mono[i];
    cf.cc = (float)cc; cf.inv_h = (float)(1.0 / hh);
  }

  dim3 grid(nmat), block(256);
  hipLaunchKernelGGL(logm_kernel, grid, block, 0, stream, X, Y, cf);
}

// Round 8
// 182.665 us; speedup vs baseline: 1.0015x; 1.0015x over previous
//
#include <hip/hip_runtime.h>
#include <math.h>
#include <string.h>

#define CDIM 64
#define LDSW 72   // row stride in bf16 elems (144 B): b128 frag reads measured conflict-free
#define DEG  5    // Chebyshev tail on [1,7.5] ~5.6e-3; Paterson-Stockmeyer s=2 -> 3 matmuls

struct Coefs { float a[DEG + 1]; float cc; float inv_h; };

typedef __attribute__((ext_vector_type(8)))  short short8;      // 8 bf16 = 4 VGPRs (MFMA A/B frag)
typedef __attribute__((ext_vector_type(16))) float floatx16;    // MFMA C/D
typedef __attribute__((ext_vector_type(4)))  float floatx4;     // packed global I/O
typedef __attribute__((ext_vector_type(4)))  unsigned short ushort4v;  // packed LDS I/O

// f32 -> bf16 round-to-nearest-even (bit trick, ~2^-9 max rel err).
__device__ __forceinline__ unsigned short f2bf_rn(float x) {
  const unsigned u = __builtin_bit_cast(unsigned, x);
  return (unsigned short)((u + 0x7FFFu + ((u >> 16) & 1u)) >> 16);
}
__device__ __forceinline__ float bf2f(unsigned short s) {
  return __builtin_bit_cast(float, ((unsigned)s) << 16);
}

struct Frags  { short8 h[4]; short8 l[4]; };   // hi+lo fragments = 32 VGPRs
struct FragsH { short8 h[4]; };                // hi-only fragments = 16 VGPRs

__device__ __forceinline__ void load_frags(const unsigned short* __restrict__ Ph,
                                           const unsigned short* __restrict__ Pl,
                                           int row, int ko, Frags* f) {
#pragma unroll
  for (int kk = 0; kk < 4; ++kk) {
    f->h[kk] = *(const short8*)(Ph + row * LDSW + kk * 16 + ko);
    f->l[kk] = *(const short8*)(Pl + row * LDSW + kk * 16 + ko);
  }
}

__device__ __forceinline__ void load_frags_h(const unsigned short* __restrict__ Ph,
                                             int row, int ko, FragsH* f) {
#pragma unroll
  for (int kk = 0; kk < 4; ++kk)
    f->h[kk] = *(const short8*)(Ph + row * LDSW + kk * 16 + ko);
}

// Single-chain h*h 32x32 tile product (downstream matmuls: dropped l-terms
// are ~2^-9-relative, scaled by small coefficients -> ~1e-3 output error).
__device__ __forceinline__ floatx16 mm_h(const FragsH& a, const FragsH& b) {
  floatx16 c;
#pragma unroll
  for (int i = 0; i < 16; ++i) c[i] = 0.0f;
#pragma unroll
  for (int kk = 0; kk < 4; ++kk)
    c = __builtin_amdgcn_mfma_f32_32x32x16_bf16(a.h[kk], b.h[kk], c, 0, 0, 0);
  return c;
}

// R8: all matrices here are SYMMETRIC, so every LDS buffer (and the X read /
// Y write) is stored TRANSPOSED: element (row,col) lives at [col][row].
// Content is the same matrix; frag loads are unchanged. The win: epilogue
// indices become col*LDSW + rows[r], and within an accumulator quad
// (r = 4q..4q+3) rows[r] are CONSECUTIVE -> 4 bf16 = one ds b64,
// 4 f32 = one global dwordx4. Plus rM1[16] in regs (VGPR slack is large)
// removes all scalar M1 re-reads. Cuts per-thread DS ops ~136->~40,
// global 32->8, VALU ~875->~550 -- attacks the measured issue floor.
__global__ void __launch_bounds__(256, 4)
logm_kernel(const float* __restrict__ X, float* __restrict__ Y, Coefs cf) {
  // Buffers: A(hi+lo) = M1 (never overwritten), Ch = M2 then Q1 (hi-only, RN).
  // 3 x 9216 B = 27.6 KB.
  __shared__ __align__(16) unsigned short Ah[CDIM * LDSW], Al[CDIM * LDSW];
  __shared__ __align__(16) unsigned short Ch[CDIM * LDSW];

  const int tid  = threadIdx.x;
  const int lane = tid & 63;
  const int w    = tid >> 6;
  const int m    = blockIdx.x;

  const float* __restrict__ Xm = X + (size_t)m * (CDIM * CDIM);
  float* __restrict__ Ym       = Y + (size_t)m * (CDIM * CDIM);

  const int R     = (w >> 1) * 32;
  const int Cc    = (w & 1) * 32;
  const int l31   = lane & 31;
  const int half  = lane >> 5;
  const int arow  = R + l31;
  const int brow  = Cc + l31;
  const int ko    = half * 8;
  const int col   = Cc + l31;
  const int base0 = R + 4 * half;   // quad q covers rows base0+8q .. +3
  // C/D layout: r=4q+j -> row = base0 + 8q + j, col = col  [verified m74/m101]

  // ---- stage: read X column-wise (dwordx4, symmetric => same data),
  //      M1 -> A hi/lo transposed-packed (b64 per quad); keep t in rM1 ----
  float rM1[16];
  {
    const float* __restrict__ Xc = Xm + col * CDIM;
#pragma unroll
    for (int q = 0; q < 4; ++q) {
      const int br = base0 + 8 * q;
      const floatx4 xv = *(const floatx4*)(Xc + br);
      ushort4v hv, lv;
#pragma unroll
      for (int j = 0; j < 4; ++j) {
        float x = xv[j];
        if (br + j == col) x -= cf.cc;
        const float t = x * cf.inv_h;
        rM1[4 * q + j] = t;
        const unsigned short hu = f2bf_rn(t);
        hv[j] = hu;
        lv[j] = f2bf_rn(t - bf2f(hu));
      }
      const int idxT = col * LDSW + br;
      *(ushort4v*)(Ah + idxT) = hv;
      *(ushort4v*)(Al + idxT) = lv;
    }
  }
  __syncthreads();

  // ---- mm1: M2 = M1*M1 (full 3-chain compensation; feeds 2 more multiplies).
  //      fa loaded whole (h half reused as mm2's A-operand); fb slab-wise to
  //      cap the register peak (M1 symmetric -> brow rows are B-columns). ----
  Frags fa;
  load_frags(Ah, Al, arow, ko, &fa);
  floatx16 c1, c2;
#pragma unroll
  for (int i = 0; i < 16; ++i) { c1[i] = 0.0f; c2[i] = 0.0f; }
#pragma unroll
  for (int kk = 0; kk < 4; ++kk) {
    const short8 fbh = *(const short8*)(Ah + brow * LDSW + kk * 16 + ko);
    const short8 fbl = *(const short8*)(Al + brow * LDSW + kk * 16 + ko);
    c1 = __builtin_amdgcn_mfma_f32_32x32x16_bf16(fa.h[kk], fbh, c1, 0, 0, 0);
    c2 = __builtin_amdgcn_mfma_f32_32x32x16_bf16(fa.h[kk], fbl, c2, 0, 0, 0);
    c2 = __builtin_amdgcn_mfma_f32_32x32x16_bf16(fa.l[kk], fbh, c2, 0, 0, 0);
  }
  floatx16 accM2;
#pragma unroll
  for (int i = 0; i < 16; ++i) accM2[i] = c1[i] + c2[i];
#pragma unroll
  for (int q = 0; q < 4; ++q) {
    ushort4v hv;
#pragma unroll
    for (int j = 0; j < 4; ++j) hv[j] = f2bf_rn(accM2[4 * q + j]);
    *(ushort4v*)(Ch + col * LDSW + base0 + 8 * q) = hv;   // M2 transposed-packed
  }
  __syncthreads();   // M2 published; all A reads for mm1 done

  // ---- mm2: T = M1*M2 (h-only; fa.h reused, fa.l dead);
  //      Q1 = a5*T + a4*accM2(f32 exact) + a3*rM1(regs) + a2*I ----
  FragsH fah, fm2;
#pragma unroll
  for (int kk = 0; kk < 4; ++kk) fah.h[kk] = fa.h[kk];
  load_frags_h(Ch, brow, ko, &fm2);      // M2 B-operand via symmetry; kept for mm3
  floatx16 accT = mm_h(fah, fm2);
  __syncthreads();                       // all Ch (M2) cross-tile reads complete
#pragma unroll
  for (int q = 0; q < 4; ++q) {
    const int br = base0 + 8 * q;
    ushort4v hv;
#pragma unroll
    for (int j = 0; j < 4; ++j) {
      const int r = 4 * q + j;
      float v = cf.a[5] * accT[r] + cf.a[4] * accM2[r] + cf.a[3] * rM1[r];
      if (br + j == col) v += cf.a[2];
      hv[j] = f2bf_rn(v);
    }
    *(ushort4v*)(Ch + col * LDSW + br) = hv;   // Q1 over M2, transposed-packed
  }
  __syncthreads();

  // ---- mm3: out = Q1*M2 (h-only) + a1*rM1 + a0*I -> global, transposed
  //      dwordx4 (out symmetric; un-transposes on store) ----
  FragsH fq1;
  load_frags_h(Ch, arow, ko, &fq1);
  floatx16 accF = mm_h(fq1, fm2);
  {
    float* __restrict__ Yc = Ym + col * CDIM;
#pragma unroll
    for (int q = 0; q < 4; ++q) {
      const int br = base0 + 8 * q;
      floatx4 pv;
#pragma unroll
      for (int j = 0; j < 4; ++j) {
        const int r = 4 * q + j;
        float p = accF[r] + cf.a[1] * rM1[r];
        if (br + j == col) p += cf.a[0];
        pv[j] = p;
      }
      *(floatx4*)(Yc + br) = pv;
    }
  }
}

extern "C" void kernel_launch(void* const* d_in, const int* in_sizes, int n_in,
                              void* d_out, int out_size, void* d_ws, size_t ws_size,
                              hipStream_t stream) {
  const float* X = (const float*)d_in[0];
  float* Y = (float*)d_out;
  const int nmat = in_sizes[0] / (CDIM * CDIM);

  // Chebyshev coefficients of log on [lo,hi] -> monomial basis in t=(x-cc)/hh.
  // Analytic: log(cc+hh*t) = log(A) - 2*sum_k z^k/k T_k(t),  z=(-cc+sqrt(cc^2-hh^2))/hh
  Coefs cf;
  {
    const double lo = 1.0, hi = 7.5;
    const double cc = 0.5 * (lo + hi), hh = 0.5 * (hi - lo);
    const double s  = sqrt(cc * cc - hh * hh);
    const double z  = (-cc + s) / hh;
    const double A  = 0.5 * (cc + s);
    double cheb[DEG + 1];
    cheb[0] = log(A);
    double zp = 1.0;
    for (int k = 1; k <= DEG; ++k) { zp *= z; cheb[k] = -2.0 * zp / (double)k; }
    double mono[DEG + 1], Tprev[DEG + 1], Tcur[DEG + 1];
    memset(mono, 0, sizeof(mono));
    memset(Tprev, 0, sizeof(Tprev));
    memset(Tcur, 0, sizeof(Tcur));
    Tprev[0] = 1.0; mono[0] += cheb[0];
    Tcur[1]  = 1.0; mono[1] += cheb[1];
    for (int k = 2; k <= DEG; ++k) {
      double Tn[DEG + 1];
      memset(Tn, 0, sizeof(Tn));
      for (int j = 0; j <= k; ++j) {
        double v = -Tprev[j];
        if (j > 0) v += 2.0 * Tcur[j - 1];
        Tn[j] = v;
      }
      for (int j = 0; j <= k; ++j) mono[j] += cheb[k] * Tn[j];
      for (int j = 0; j <= DEG; ++j) { Tprev[j] = Tcur[j]; Tcur[j] = Tn[j]; }
    }
    for (int i = 0; i <= DEG; ++i) cf.a[i] = (float)mono[i];
    cf.cc = (float)cc; cf.inv_h = (float)(1.0 / hh);
  }

  dim3 grid(nmat), block(256);
  hipLaunchKernelGGL(logm_kernel, grid, block, 0, stream, X, Y, cf);
}

// Round 9
// 179.746 us; speedup vs baseline: 1.0178x; 1.0162x over previous
//
#include <hip/hip_runtime.h>
#include <math.h>
#include <string.h>

#define CDIM 64
#define LDSW 72   // row stride in bf16 elems (144 B): b128 frag reads conflict-free (stride 36 dw)
#define DEG  5    // Chebyshev tail on [1,7.5] ~5.6e-3; Paterson-Stockmeyer s=2 -> 3 matmuls

struct Coefs { float a[DEG + 1]; float cc; float inv_h; };

typedef __attribute__((ext_vector_type(8)))  short short8;      // 8 bf16 = 4 VGPRs (MFMA A/B frag)
typedef __attribute__((ext_vector_type(16))) float floatx16;    // MFMA C/D
typedef __attribute__((ext_vector_type(4)))  float floatx4;     // packed global I/O
typedef __attribute__((ext_vector_type(4)))  unsigned short ushort4v;  // packed LDS I/O

// f32 -> bf16 round-to-nearest-even (bit trick, ~2^-9 max rel err).
__device__ __forceinline__ unsigned short f2bf_rn(float x) {
  const unsigned u = __builtin_bit_cast(unsigned, x);
  return (unsigned short)((u + 0x7FFFu + ((u >> 16) & 1u)) >> 16);
}
__device__ __forceinline__ float bf2f(unsigned short s) {
  return __builtin_bit_cast(float, ((unsigned)s) << 16);
}

struct Frags  { short8 h[4]; short8 l[4]; };   // hi+lo fragments = 32 VGPRs
struct FragsH { short8 h[4]; };                // hi-only fragments = 16 VGPRs

__device__ __forceinline__ void load_frags(const unsigned short* __restrict__ Ph,
                                           const unsigned short* __restrict__ Pl,
                                           int row, int ko, Frags* f) {
#pragma unroll
  for (int kk = 0; kk < 4; ++kk) {
    f->h[kk] = *(const short8*)(Ph + row * LDSW + kk * 16 + ko);
    f->l[kk] = *(const short8*)(Pl + row * LDSW + kk * 16 + ko);
  }
}

__device__ __forceinline__ void load_frags_h(const unsigned short* __restrict__ Ph,
                                             int row, int ko, FragsH* f) {
#pragma unroll
  for (int kk = 0; kk < 4; ++kk)
    f->h[kk] = *(const short8*)(Ph + row * LDSW + kk * 16 + ko);
}

// Single-chain h*h 32x32 tile product (downstream matmuls: dropped l-terms
// are ~2^-9-relative, scaled by small coefficients -> ~1e-3 output error).
__device__ __forceinline__ floatx16 mm_h(const FragsH& a, const FragsH& b) {
  floatx16 c;
#pragma unroll
  for (int i = 0; i < 16; ++i) c[i] = 0.0f;
#pragma unroll
  for (int kk = 0; kk < 4; ++kk)
    c = __builtin_amdgcn_mfma_f32_32x32x16_bf16(a.h[kk], b.h[kk], c, 0, 0, 0);
  return c;
}

// R9: barrier reduction 4 -> 3. Q1 gets its own buffer Dh (instead of
// overwriting Ch in place), deleting the mid-mm2 "all M2 reads done" barrier.
// LDS 27.6 -> 36.9 KB still fits 4 blocks/CU (147.5 <= 160 KB). Zero register
// impact (2-chain mm1 kept: +16 AGPR for a 3rd chain risks the 128-reg cliff).
// R8's bank conflicts measured irrelevant (64 cy/wave) -- left alone; any fix
// breaks b128 16-B alignment and costs more in extra ds_read issue.
__global__ void __launch_bounds__(256, 4)
logm_kernel(const float* __restrict__ X, float* __restrict__ Y, Coefs cf) {
  // Buffers (all stored TRANSPOSED, [col][row]; symmetric matrices => same data):
  // A(hi+lo) = M1, Ch = M2, Dh = Q1. 4 x 9216 B = 36,864 B.
  __shared__ __align__(16) unsigned short Ah[CDIM * LDSW], Al[CDIM * LDSW];
  __shared__ __align__(16) unsigned short Ch[CDIM * LDSW];
  __shared__ __align__(16) unsigned short Dh[CDIM * LDSW];

  const int tid  = threadIdx.x;
  const int lane = tid & 63;
  const int w    = tid >> 6;
  const int m    = blockIdx.x;

  const float* __restrict__ Xm = X + (size_t)m * (CDIM * CDIM);
  float* __restrict__ Ym       = Y + (size_t)m * (CDIM * CDIM);

  const int R     = (w >> 1) * 32;
  const int Cc    = (w & 1) * 32;
  const int l31   = lane & 31;
  const int half  = lane >> 5;
  const int arow  = R + l31;
  const int brow  = Cc + l31;
  const int ko    = half * 8;
  const int col   = Cc + l31;
  const int base0 = R + 4 * half;   // quad q covers rows base0+8q .. +3
  // C/D layout: r=4q+j -> row = base0 + 8q + j, col = col  [verified m74/m101]

  // ---- stage: read X column-wise (dwordx4, symmetric => same data),
  //      M1 -> A hi/lo transposed-packed (b64 per quad); keep t in rM1 ----
  float rM1[16];
  {
    const float* __restrict__ Xc = Xm + col * CDIM;
#pragma unroll
    for (int q = 0; q < 4; ++q) {
      const int br = base0 + 8 * q;
      const floatx4 xv = *(const floatx4*)(Xc + br);
      ushort4v hv, lv;
#pragma unroll
      for (int j = 0; j < 4; ++j) {
        float x = xv[j];
        if (br + j == col) x -= cf.cc;
        const float t = x * cf.inv_h;
        rM1[4 * q + j] = t;
        const unsigned short hu = f2bf_rn(t);
        hv[j] = hu;
        lv[j] = f2bf_rn(t - bf2f(hu));
      }
      const int idxT = col * LDSW + br;
      *(ushort4v*)(Ah + idxT) = hv;
      *(ushort4v*)(Al + idxT) = lv;
    }
  }
  __syncthreads();   // B1: M1 published

  // ---- mm1: M2 = M1*M1 (full compensation, 2 acc chains).
  //      fa loaded whole (h half reused as mm2's A-operand); fb slab-wise to
  //      cap the register peak (M1 symmetric -> brow rows are B-columns). ----
  Frags fa;
  load_frags(Ah, Al, arow, ko, &fa);
  floatx16 c1, c2;
#pragma unroll
  for (int i = 0; i < 16; ++i) { c1[i] = 0.0f; c2[i] = 0.0f; }
#pragma unroll
  for (int kk = 0; kk < 4; ++kk) {
    const short8 fbh = *(const short8*)(Ah + brow * LDSW + kk * 16 + ko);
    const short8 fbl = *(const short8*)(Al + brow * LDSW + kk * 16 + ko);
    c1 = __builtin_amdgcn_mfma_f32_32x32x16_bf16(fa.h[kk], fbh, c1, 0, 0, 0);
    c2 = __builtin_amdgcn_mfma_f32_32x32x16_bf16(fa.h[kk], fbl, c2, 0, 0, 0);
    c2 = __builtin_amdgcn_mfma_f32_32x32x16_bf16(fa.l[kk], fbh, c2, 0, 0, 0);
  }
  floatx16 accM2;
#pragma unroll
  for (int i = 0; i < 16; ++i) accM2[i] = c1[i] + c2[i];
#pragma unroll
  for (int q = 0; q < 4; ++q) {
    ushort4v hv;
#pragma unroll
    for (int j = 0; j < 4; ++j) hv[j] = f2bf_rn(accM2[4 * q + j]);
    *(ushort4v*)(Ch + col * LDSW + base0 + 8 * q) = hv;   // M2 transposed-packed
  }
  __syncthreads();   // B2: M2 published

  // ---- mm2: T = M1*M2 (h-only; fa.h reused, fa.l dead);
  //      Q1 = a5*T + a4*accM2(f32 exact) + a3*rM1(regs) + a2*I -> Dh
  //      (own buffer: no WAR on Ch, so no barrier between read and write) ----
  FragsH fah, fm2;
#pragma unroll
  for (int kk = 0; kk < 4; ++kk) fah.h[kk] = fa.h[kk];
  load_frags_h(Ch, brow, ko, &fm2);      // M2 B-operand via symmetry; kept for mm3
  floatx16 accT = mm_h(fah, fm2);
#pragma unroll
  for (int q = 0; q < 4; ++q) {
    const int br = base0 + 8 * q;
    ushort4v hv;
#pragma unroll
    for (int j = 0; j < 4; ++j) {
      const int r = 4 * q + j;
      float v = cf.a[5] * accT[r] + cf.a[4] * accM2[r] + cf.a[3] * rM1[r];
      if (br + j == col) v += cf.a[2];
      hv[j] = f2bf_rn(v);
    }
    *(ushort4v*)(Dh + col * LDSW + br) = hv;   // Q1 transposed-packed
  }
  __syncthreads();   // B3: Q1 published

  // ---- mm3: out = Q1*M2 (h-only) + a1*rM1 + a0*I -> global, transposed
  //      dwordx4 (out symmetric; un-transposes on store) ----
  FragsH fq1;
  load_frags_h(Dh, arow, ko, &fq1);
  floatx16 accF = mm_h(fq1, fm2);
  {
    float* __restrict__ Yc = Ym + col * CDIM;
#pragma unroll
    for (int q = 0; q < 4; ++q) {
      const int br = base0 + 8 * q;
      floatx4 pv;
#pragma unroll
      for (int j = 0; j < 4; ++j) {
        const int r = 4 * q + j;
        float p = accF[r] + cf.a[1] * rM1[r];
        if (br + j == col) p += cf.a[0];
        pv[j] = p;
      }
      *(floatx4*)(Yc + br) = pv;
    }
  }
}

extern "C" void kernel_launch(void* const* d_in, const int* in_sizes, int n_in,
                              void* d_out, int out_size, void* d_ws, size_t ws_size,
                              hipStream_t stream) {
  const float* X = (const float*)d_in[0];
  float* Y = (float*)d_out;
  const int nmat = in_sizes[0] / (CDIM * CDIM);

  // Chebyshev coefficients of log on [lo,hi] -> monomial basis in t=(x-cc)/hh.
  // Analytic: log(cc+hh*t) = log(A) - 2*sum_k z^k/k T_k(t),  z=(-cc+sqrt(cc^2-hh^2))/hh
  Coefs cf;
  {
    const double lo = 1.0, hi = 7.5;
    const double cc = 0.5 * (lo + hi), hh = 0.5 * (hi - lo);
    const double s  = sqrt(cc * cc - hh * hh);
    const double z  = (-cc + s) / hh;
    const double A  = 0.5 * (cc + s);
    double cheb[DEG + 1];
    cheb[0] = log(A);
    double zp = 1.0;
    for (int k = 1; k <= DEG; ++k) { zp *= z; cheb[k] = -2.0 * zp / (double)k; }
    double mono[DEG + 1], Tprev[DEG + 1], Tcur[DEG + 1];
    memset(mono, 0, sizeof(mono));
    memset(Tprev, 0, sizeof(Tprev));
    memset(Tcur, 0, sizeof(Tcur));
    Tprev[0] = 1.0; mono[0] += cheb[0];
    Tcur[1]  = 1.0; mono[1] += cheb[1];
    for (int k = 2; k <= DEG; ++k) {
      double Tn[DEG + 1];
      memset(Tn, 0, sizeof(Tn));
      for (int j = 0; j <= k; ++j) {
        double v = -Tprev[j];
        if (j > 0) v += 2.0 * Tcur[j - 1];
        Tn[j] = v;
      }
      for (int j = 0; j <= k; ++j) mono[j] += cheb[k] * Tn[j];
      for (int j = 0; j <= DEG; ++j) { Tprev[j] = Tcur[j]; Tcur[j] = Tn[j]; }
    }
    for (int i = 0; i <= DEG; ++i) cf.a[i] = (float)mono[i];
    cf.cc = (float)cc; cf.inv_h = (float)(1.0 / hh);
  }

  dim3 grid(nmat), block(256);
  hipLaunchKernelGGL(logm_kernel, grid, block, 0, stream, X, Y, cf);
}